// Round 13
// baseline (392.706 us; speedup 1.0000x reference)
//
#include <hip/hip_runtime.h>
#include <hip/hip_bf16.h>

#define NN 50000
#define EE 600000
#define DD 128
#define LL 4
#define CC 10
#define GG 512
#define BN_EPS 1e-5f
#define ELLW 48

#define EB_BLOCKS ((EE + 255) / 256)          // 2344
#define PW_BLOCKS ((8 * DD * DD) / 256)       // 512
#define GP_BLOCKS 3
#define AGG_BLOCKS (NN / 8)                   // 6250 (2 nodes per wave, 4 waves)
#define ZERO_N (8 * 256 + NN)                 // statb(2048 dwords) + cursor(NN)
#define ZERO_BLOCKS ((ZERO_N + 255) / 256)

typedef __attribute__((ext_vector_type(8))) short short8;
typedef __attribute__((ext_vector_type(4))) float f32x4;

__device__ __forceinline__ unsigned short f2b(float f) {
    union { float f; unsigned int u; } v; v.f = f;
    unsigned int u = v.u;
    unsigned int r = (u + 0x7fffu + ((u >> 16) & 1u)) >> 16;
    return (unsigned short)r;
}
__device__ __forceinline__ float b2f(unsigned short h) {
    union { unsigned int u; float f; } v; v.u = ((unsigned int)h) << 16;
    return v.f;
}

// ---------------- zero statb + cursor ----------------

__global__ __launch_bounds__(256) void zero_kernel(int* __restrict__ base) {
    int i = blockIdx.x * 256 + threadIdx.x;
    if (i < ZERO_N) base[i] = 0;
}

// ---------------- setup: pool/cvt of x + ELL fill (nt stores) + prep_weights + gptr ----------------

__global__ __launch_bounds__(256) void setup_kernel(const int* __restrict__ src,
                                                    const int* __restrict__ dst,
                                                    int* __restrict__ cursor,
                                                    int* __restrict__ ell,
                                                    const float* __restrict__ Wc1,
                                                    const float* __restrict__ Wc2,
                                                    unsigned short* __restrict__ WTb,
                                                    const int* __restrict__ batch,
                                                    int* __restrict__ gptr,
                                                    const float* __restrict__ x,
                                                    unsigned short* __restrict__ xb,
                                                    float* __restrict__ pooled0) {
    int b = blockIdx.x;
    if (b < GG) {
        // one block per graph: bf16-convert rows + pool raw x
        __shared__ float2 red[4][64];
        const int g = b;
        int lo = 0, hi = NN;
        while (lo < hi) { int mid = (lo + hi) >> 1; if (batch[mid] < g) lo = mid + 1; else hi = mid; }
        int beg = lo;
        hi = NN;
        while (lo < hi) { int mid = (lo + hi) >> 1; if (batch[mid] < g + 1) lo = mid + 1; else hi = mid; }
        int end = lo;
        int wave = threadIdx.x >> 6, lane = threadIdx.x & 63;
        float ax = 0.f, ay = 0.f;
        for (int r = beg + wave; r < end; r += 4) {
            float2 v = ((const float2*)(x + (size_t)r * DD))[lane];
            ax += v.x; ay += v.y;
            ((unsigned int*)(xb + (size_t)r * DD))[lane] =
                (unsigned int)f2b(v.x) | ((unsigned int)f2b(v.y) << 16);
        }
        red[wave][lane] = make_float2(ax, ay);
        __syncthreads();
        if (threadIdx.x < 64) {
            float2 a = red[0][lane], bb = red[1][lane], c = red[2][lane], d = red[3][lane];
            ((float2*)pooled0)[(size_t)g * 64 + lane] =
                make_float2(a.x + bb.x + c.x + d.x, a.y + bb.y + c.y + d.y);
        }
    } else if (b < GG + EB_BLOCKS) {
        int e = (b - GG) * 256 + threadIdx.x;
        if (e < EE) {
            int d = dst[e];
            int slot = atomicAdd(&cursor[d], 1);
            if (slot < ELLW)
                __builtin_nontemporal_store(src[e], &ell[(size_t)d * ELLW + slot]);
        }
    } else if (b < GG + EB_BLOCKS + PW_BLOCKS) {
        int idx = (b - GG - EB_BLOCKS) * 256 + threadIdx.x;   // 131072 total
        int mat = idx >> 14;
        int n = (idx >> 7) & 127;
        int k = idx & 127;
        const float* srcp = (mat < 4) ? (Wc1 + (size_t)mat * DD * DD)
                                      : (Wc2 + (size_t)(mat - 4) * DD * DD);
        WTb[idx] = f2b(srcp[k * DD + n]);
    } else {
        int g = (b - GG - EB_BLOCKS - PW_BLOCKS) * 256 + threadIdx.x;
        if (g > GG) return;
        int lo = 0, hi = NN;
        while (lo < hi) {
            int mid = (lo + hi) >> 1;
            if (batch[mid] < g) lo = mid + 1; else hi = mid;
        }
        gptr[g] = lo;
    }
}

// ---------------- aggregation: 2 nodes per wave, predicated gathers ----------------
// out[n] = t(h[n]) + sum_{src} t(h[src]),  t = BN-affine+ReLU if BN else identity.
// Wave layout: slot = lane>>4 (edge slot), seg = lane&15 (16B column segment).
// nA is even; the wave handles nodes nA and nA+1.

template <bool BN>
__device__ __forceinline__ void agg_pair(int nA, const unsigned short* __restrict__ hb,
                                         const int* __restrict__ ell,
                                         const int* __restrict__ degA,
                                         const float* __restrict__ stats,
                                         const float* __restrict__ gamma,
                                         const float* __restrict__ beta,
                                         unsigned short* __restrict__ outb) {
    const int lane = threadIdx.x & 63;
    const int seg = lane & 15;
    const int slot = lane >> 4;

    float A[8], B[8];
    if (BN) {
#pragma unroll
        for (int j = 0; j < 8; ++j) {
            int c = seg * 8 + j;
            float mu = stats[c] * (1.0f / NN);
            float var = stats[DD + c] * (1.0f / NN) - mu * mu;
            A[j] = gamma[c] * rsqrtf(var + BN_EPS);
            B[j] = beta[c] - mu * A[j];
        }
    }

    const uint4* hb4 = (const uint4*)hb;            // row stride = 16 uint4
    uint4 self = make_uint4(0u, 0u, 0u, 0u);
    if (slot < 2) self = hb4[(size_t)(nA + slot) * 16 + seg];

    float accA[8], accB[8];
#pragma unroll
    for (int j = 0; j < 8; ++j) { accA[j] = 0.f; accB[j] = 0.f; }

    const int* rowA = ell + (size_t)nA * ELLW;
    const int* rowB = rowA + ELLW;
    const int dgA = min(degA[nA], ELLW);
    const int dgB = min(degA[nA + 1], ELLW);
    const int dgM = max(dgA, dgB);

    for (int e = 0; e < dgM; e += 16) {
        bool vA[4], vB[4];
        int iA[4], iB[4];
#pragma unroll
        for (int i = 0; i < 4; ++i) {
            int t = e + i * 4 + slot;
            vA[i] = (t < dgA);
            vB[i] = (t < dgB);
            iA[i] = rowA[t];   // in-bounds (<= ELLW-1); value unused when !vA
            iB[i] = rowB[t];
        }
        uint4 a[4], b[4];
#pragma unroll
        for (int i = 0; i < 4; ++i) {
            if (vA[i]) a[i] = hb4[(size_t)iA[i] * 16 + seg];
        }
#pragma unroll
        for (int i = 0; i < 4; ++i) {
            if (vB[i]) b[i] = hb4[(size_t)iB[i] * 16 + seg];
        }
#pragma unroll
        for (int i = 0; i < 4; ++i) {
            if (vA[i]) {
#pragma unroll
                for (int j = 0; j < 4; ++j) {
                    unsigned int u = ((unsigned int*)&a[i])[j];
                    float x = b2f((unsigned short)(u & 0xffff));
                    float y = b2f((unsigned short)(u >> 16));
                    if (BN) {
                        x = fmaxf(0.f, fmaf(x, A[2 * j], B[2 * j]));
                        y = fmaxf(0.f, fmaf(y, A[2 * j + 1], B[2 * j + 1]));
                    }
                    accA[2 * j] += x;
                    accA[2 * j + 1] += y;
                }
            }
            if (vB[i]) {
#pragma unroll
                for (int j = 0; j < 4; ++j) {
                    unsigned int u = ((unsigned int*)&b[i])[j];
                    float x = b2f((unsigned short)(u & 0xffff));
                    float y = b2f((unsigned short)(u >> 16));
                    if (BN) {
                        x = fmaxf(0.f, fmaf(x, A[2 * j], B[2 * j]));
                        y = fmaxf(0.f, fmaf(y, A[2 * j + 1], B[2 * j + 1]));
                    }
                    accB[2 * j] += x;
                    accB[2 * j + 1] += y;
                }
            }
        }
    }

#pragma unroll
    for (int j = 0; j < 8; ++j) {
        accA[j] += __shfl_xor(accA[j], 16);
        accA[j] += __shfl_xor(accA[j], 32);
        accB[j] += __shfl_xor(accB[j], 16);
        accB[j] += __shfl_xor(accB[j], 32);
    }

    if (slot < 2) {
        uint4 o;
#pragma unroll
        for (int j = 0; j < 4; ++j) {
            unsigned int u = ((unsigned int*)&self)[j];
            float x = b2f((unsigned short)(u & 0xffff));
            float y = b2f((unsigned short)(u >> 16));
            if (BN) {
                x = fmaxf(0.f, fmaf(x, A[2 * j], B[2 * j]));
                y = fmaxf(0.f, fmaf(y, A[2 * j + 1], B[2 * j + 1]));
            }
            float sx = (slot == 0) ? accA[2 * j] : accB[2 * j];
            float sy = (slot == 0) ? accA[2 * j + 1] : accB[2 * j + 1];
            ((unsigned int*)&o)[j] =
                (unsigned int)f2b(sx + x) | ((unsigned int)f2b(sy + y) << 16);
        }
        ((uint4*)outb)[(size_t)(nA + slot) * 16 + seg] = o;
    }
}

__global__ __launch_bounds__(256) void aggregate_x(const unsigned short* __restrict__ hb,
                                                   const int* __restrict__ ell,
                                                   const int* __restrict__ degA,
                                                   unsigned short* __restrict__ outb) {
    int nA = blockIdx.x * 8 + (threadIdx.x >> 6) * 2;   // NN % 8 == 0: no bounds check
    agg_pair<false>(nA, hb, ell, degA, nullptr, nullptr, nullptr, outb);
}

// ---------------- MFMA GEMM, W in registers: Out = (bn?)(Z) @ W + bias, + stats ----------------

__global__ __launch_bounds__(256, 2) void gemm_mfma(
    const unsigned short* __restrict__ Ab,   // [NN][128] bf16
    const unsigned short* __restrict__ WTb,  // [128][128] bf16 (WT[n][k])
    const float* __restrict__ bias,
    const float* __restrict__ bnStatsIn,     // null => raw input
    const float* __restrict__ gamma, const float* __restrict__ beta,
    unsigned short* __restrict__ Outb,       // [NN][128] bf16
    float* __restrict__ statsOut)            // [0..127]=colsum, [128..255]=colsumsq
{
    __shared__ unsigned short As[128 * 128];  // 32 KB, XOR-swizzled rows
    __shared__ float AbnS[DD], BbnS[DD];
    __shared__ float colred[2][DD];

    const int tid = threadIdx.x;
    const int row0 = blockIdx.x * 128;
    const bool doBn = (bnStatsIn != nullptr);
    const int lane = tid & 63;
    const int fr = lane & 15, fq = lane >> 4;

    // B fragments: all of W in registers (32 KB total, L2-hot). 8n x 4kk x 16B/lane.
    short8 bfrag[8][4];
#pragma unroll
    for (int n = 0; n < 8; ++n)
#pragma unroll
        for (int kk = 0; kk < 4; ++kk)
            bfrag[n][kk] = *(const short8*)((const char*)WTb + (n * 16 + fr) * 256 + kk * 64 + fq * 16);

    if (tid < DD) {
        colred[0][tid] = 0.f;
        colred[1][tid] = 0.f;
        if (doBn) {
            float mu = bnStatsIn[tid] * (1.0f / NN);
            float var = bnStatsIn[DD + tid] * (1.0f / NN) - mu * mu;
            float A = gamma[tid] * rsqrtf(var + BN_EPS);
            AbnS[tid] = A;
            BbnS[tid] = beta[tid] - mu * A;
        }
    }
    if (doBn) __syncthreads();

    // stage A tile (optional BN+ReLU on load)
#pragma unroll
    for (int i = 0; i < 8; ++i) {
        int c = tid + i * 256;
        int row = c >> 4, seg = c & 15;
        int gr = row0 + row;
        uint4 v = make_uint4(0u, 0u, 0u, 0u);
        if (gr < NN) v = ((const uint4*)(Ab + (size_t)gr * DD))[seg];
        if (doBn) {
            int k0 = seg * 8;
#pragma unroll
            for (int e = 0; e < 4; ++e) {
                unsigned int u = ((unsigned int*)&v)[e];
                int cidx = k0 + 2 * e;
                float lo = fmaxf(0.f, fmaf(b2f((unsigned short)(u & 0xffff)), AbnS[cidx], BbnS[cidx]));
                float hi = fmaxf(0.f, fmaf(b2f((unsigned short)(u >> 16)), AbnS[cidx + 1], BbnS[cidx + 1]));
                ((unsigned int*)&v)[e] = (unsigned int)f2b(lo) | ((unsigned int)f2b(hi) << 16);
            }
        }
        int byte = (row * 256 + seg * 16) ^ ((row & 7) << 4);
        *(uint4*)((char*)As + byte) = v;
    }
    __syncthreads();

    const int wave = tid >> 6;
    const int wr0 = wave * 32;

    f32x4 acc[2][8];
#pragma unroll
    for (int m = 0; m < 2; ++m)
#pragma unroll
        for (int n = 0; n < 8; ++n) acc[m][n] = (f32x4)0.f;

#pragma unroll
    for (int kk = 0; kk < 4; ++kk) {
        int kbyte = kk * 64 + fq * 16;
        short8 a[2];
#pragma unroll
        for (int m = 0; m < 2; ++m) {
            int row = wr0 + m * 16 + fr;
            a[m] = *(const short8*)((const char*)As + ((row * 256 + kbyte) ^ ((row & 7) << 4)));
        }
#pragma unroll
        for (int m = 0; m < 2; ++m)
#pragma unroll
            for (int n = 0; n < 8; ++n)
                acc[m][n] = __builtin_amdgcn_mfma_f32_16x16x32_bf16(a[m], bfrag[n][kk], acc[m][n], 0, 0, 0);
    }

    float bias_n[8], s[8], q[8];
#pragma unroll
    for (int n = 0; n < 8; ++n) {
        bias_n[n] = bias[n * 16 + fr];
        s[n] = 0.f;
        q[n] = 0.f;
    }
#pragma unroll
    for (int m = 0; m < 2; ++m) {
        int rbase = row0 + wr0 + m * 16 + fq * 4;
#pragma unroll
        for (int j = 0; j < 4; ++j) {
            int gr = rbase + j;           // uniform across the 16-lane fr group
            if (gr < NN) {
#pragma unroll
                for (int n = 0; n < 8; ++n) {
                    float o = acc[m][n][j] + bias_n[n];
                    unsigned short ob = f2b(o);
                    unsigned short pb = (unsigned short)__shfl_xor((int)ob, 1);
                    s[n] += o;
                    q[n] += o * o;
                    if (!(fr & 1)) {
                        unsigned int pack = (unsigned int)ob | ((unsigned int)pb << 16);
                        *(unsigned int*)(Outb + (size_t)gr * DD + n * 16 + fr) = pack;
                    }
                }
            }
        }
    }
#pragma unroll
    for (int n = 0; n < 8; ++n) {
        s[n] += __shfl_xor(s[n], 16);
        s[n] += __shfl_xor(s[n], 32);
        q[n] += __shfl_xor(q[n], 16);
        q[n] += __shfl_xor(q[n], 32);
    }
    if (fq == 0) {
#pragma unroll
        for (int n = 0; n < 8; ++n) {
            atomicAdd(&colred[0][n * 16 + fr], s[n]);
            atomicAdd(&colred[1][n * 16 + fr], q[n]);
        }
    }
    __syncthreads();
    if (tid < DD) {
        atomicAdd(&statsOut[tid], colred[0][tid]);
        atomicAdd(&statsOut[DD + tid], colred[1][tid]);
    }
}

// ---------------- post_layer: bn_pool (blocks < GG) + next-layer aggregate (rest) ----------------

template <bool LAST>
__global__ __launch_bounds__(256) void post_layer(
    const unsigned short* __restrict__ Z,      // z2b of this layer
    const float* __restrict__ stats,           // statb (2l+1)
    const float* __restrict__ gamma,           // g_out[l]
    const float* __restrict__ beta,            // b_out[l]
    const int* __restrict__ gptr,
    const int* __restrict__ ell,
    const int* __restrict__ degA,
    float* __restrict__ pooledDst,             // pooled + (l+1)*GG*DD
    unsigned short* __restrict__ aggOut,       // aggb for next layer (unused if LAST)
    const float* __restrict__ pooledAll,       // pooled base (LAST only)
    const float* __restrict__ fcW,
    const float* __restrict__ fcb,
    float* __restrict__ out)
{
    const int bid = blockIdx.x;
    if (bid < GG) {
        __shared__ float2 red[4][64];
        __shared__ float p4[DD];
        const int g = bid;
        const int wave = threadIdx.x >> 6, lane = threadIdx.x & 63;
        const int c0 = lane * 2, c1 = c0 + 1;
        float mu0 = stats[c0] * (1.0f / NN);
        float var0 = stats[DD + c0] * (1.0f / NN) - mu0 * mu0;
        float A0 = gamma[c0] * rsqrtf(var0 + BN_EPS);
        float B0 = beta[c0] - mu0 * A0;
        float mu1 = stats[c1] * (1.0f / NN);
        float var1 = stats[DD + c1] * (1.0f / NN) - mu1 * mu1;
        float A1 = gamma[c1] * rsqrtf(var1 + BN_EPS);
        float B1 = beta[c1] - mu1 * A1;

        float ax = 0.f, ay = 0.f;
        int beg = gptr[g], end = gptr[g + 1];
        for (int r = beg + wave; r < end; r += 4) {
            unsigned int u = ((const unsigned int*)(Z + (size_t)r * DD))[lane];
            ax += fmaxf(0.f, fmaf(b2f((unsigned short)(u & 0xffff)), A0, B0));
            ay += fmaxf(0.f, fmaf(b2f((unsigned short)(u >> 16)), A1, B1));
        }
        red[wave][lane] = make_float2(ax, ay);
        __syncthreads();
        if (threadIdx.x < 64) {
            float2 a = red[0][lane], b = red[1][lane], c = red[2][lane], d = red[3][lane];
            float2 r2 = make_float2(a.x + b.x + c.x + d.x, a.y + b.y + c.y + d.y);
            ((float2*)pooledDst)[(size_t)g * 64 + lane] = r2;
            if (LAST) {
                p4[c0] = r2.x;
                p4[c1] = r2.y;
            }
        }
        if (LAST) {
            __syncthreads();
            if (threadIdx.x < 64) {
                float acc[CC];
#pragma unroll
                for (int c = 0; c < CC; ++c) acc[c] = 0.f;
                for (int i = 0; i < LL + 1; ++i) {
                    const float* Wf = fcW + (size_t)i * DD * CC;
                    for (int k = lane; k < DD; k += 64) {
                        float pv = (i == LL) ? p4[k] : pooledAll[((size_t)i * GG + g) * DD + k];
                        const float* wr = Wf + k * CC;
#pragma unroll
                        for (int c = 0; c < CC; ++c) acc[c] = fmaf(pv, wr[c], acc[c]);
                    }
                }
#pragma unroll
                for (int c = 0; c < CC; ++c)
                    for (int off = 32; off > 0; off >>= 1) acc[c] += __shfl_down(acc[c], off);
                if (lane == 0) {
#pragma unroll
                    for (int c = 0; c < CC; ++c) {
                        float b = 0.f;
                        for (int i = 0; i < LL + 1; ++i) b += fcb[i * CC + c];
                        acc[c] += b;
                    }
                    float m = acc[0];
#pragma unroll
                    for (int c = 1; c < CC; ++c) m = fmaxf(m, acc[c]);
                    float se = 0.f;
#pragma unroll
                    for (int c = 0; c < CC; ++c) se += expf(acc[c] - m);
                    float lse = m + logf(se);
#pragma unroll
                    for (int c = 0; c < CC; ++c) out[(size_t)g * CC + c] = acc[c] - lse;
                }
            }
        }
    } else {
        int nA = (bid - GG) * 8 + (threadIdx.x >> 6) * 2;
        agg_pair<true>(nA, Z, ell, degA, stats, gamma, beta, aggOut);
    }
}

// ---------------- launch ----------------

extern "C" void kernel_launch(void* const* d_in, const int* in_sizes, int n_in,
                              void* d_out, int out_size, void* d_ws, size_t ws_size,
                              hipStream_t stream) {
    const float* x     = (const float*)d_in[0];
    const int*   ei    = (const int*)d_in[1];
    const int*   batch = (const int*)d_in[2];
    const float* Wc1   = (const float*)d_in[3];
    const float* bc1   = (const float*)d_in[4];
    const float* Wc2   = (const float*)d_in[5];
    const float* bc2   = (const float*)d_in[6];
    const float* g_mid = (const float*)d_in[7];
    const float* b_mid = (const float*)d_in[8];
    const float* g_out = (const float*)d_in[9];
    const float* b_out = (const float*)d_in[10];
    const float* fcW   = (const float*)d_in[11];
    const float* fcb   = (const float*)d_in[12];
    float* out = (float*)d_out;

    char* p = (char*)d_ws;
    unsigned short* xb   = (unsigned short*)p; p += (size_t)NN * DD * 2;
    unsigned short* aggb = (unsigned short*)p; p += (size_t)NN * DD * 2;
    unsigned short* z1b  = (unsigned short*)p; p += (size_t)NN * DD * 2;
    unsigned short* z2b  = (unsigned short*)p; p += (size_t)NN * DD * 2;
    unsigned short* WTb  = (unsigned short*)p; p += (size_t)8 * DD * DD * 2;
    float* pooled = (float*)p; p += (size_t)(LL + 1) * GG * DD * 4;
    float* statb  = (float*)p; p += 8 * 256 * 4;   // contiguous with cursor: joint zero
    int* cursor = (int*)p; p += (size_t)NN * 4;    // doubles as degree array
    int* ell    = (int*)p; p += (size_t)NN * ELLW * 4;
    int* gptr   = (int*)p; p += (size_t)(GG + 16) * 4;

    const int* src = ei;
    const int* dst = ei + EE;

    zero_kernel<<<ZERO_BLOCKS, 256, 0, stream>>>((int*)statb);
    setup_kernel<<<GG + EB_BLOCKS + PW_BLOCKS + GP_BLOCKS, 256, 0, stream>>>(
        src, dst, cursor, ell, Wc1, Wc2, WTb, batch, gptr, x, xb, pooled);

    aggregate_x<<<AGG_BLOCKS, 256, 0, stream>>>(xb, ell, cursor, aggb);
    for (int l = 0; l < LL; ++l) {
        gemm_mfma<<<(NN + 127) / 128, 256, 0, stream>>>(
            aggb, WTb + (size_t)l * DD * DD, bc1 + (size_t)l * DD,
            nullptr, nullptr, nullptr,
            z1b, statb + (size_t)(2 * l) * 256);
        gemm_mfma<<<(NN + 127) / 128, 256, 0, stream>>>(
            z1b, WTb + (size_t)(4 + l) * DD * DD, bc2 + (size_t)l * DD,
            statb + (size_t)(2 * l) * 256, g_mid + (size_t)l * DD, b_mid + (size_t)l * DD,
            z2b, statb + (size_t)(2 * l + 1) * 256);
        if (l < LL - 1) {
            post_layer<false><<<GG + AGG_BLOCKS, 256, 0, stream>>>(
                z2b, statb + (size_t)(2 * l + 1) * 256,
                g_out + (size_t)l * DD, b_out + (size_t)l * DD,
                gptr, ell, cursor,
                pooled + (size_t)(l + 1) * GG * DD, aggb,
                nullptr, nullptr, nullptr, nullptr);
        } else {
            post_layer<true><<<GG, 256, 0, stream>>>(
                z2b, statb + (size_t)(2 * l + 1) * 256,
                g_out + (size_t)l * DD, b_out + (size_t)l * DD,
                gptr, ell, cursor,
                pooled + (size_t)(l + 1) * GG * DD, nullptr,
                pooled, fcW, fcb, out);
        }
    }
}

// Round 14
// 358.575 us; speedup vs baseline: 1.0952x; 1.0952x over previous
//
#include <hip/hip_runtime.h>
#include <hip/hip_bf16.h>

#define NN 50000
#define EE 600000
#define DD 128
#define LL 4
#define CC 10
#define GG 512
#define BN_EPS 1e-5f
#define ELLW 48

#define EB_BLOCKS ((EE + 255) / 256)          // 2344
#define PW_BLOCKS ((8 * DD * DD) / 256)       // 512
#define GP_BLOCKS 3
#define AGG_BLOCKS (NN / 8)                   // 6250 (2 nodes per wave, 4 waves)
#define ZERO_N (8 * 256 + NN)                 // statb(2048 dwords) + cursor(NN)
#define ZERO_BLOCKS ((ZERO_N + 255) / 256)

typedef __attribute__((ext_vector_type(8))) short short8;
typedef __attribute__((ext_vector_type(4))) float f32x4;

__device__ __forceinline__ unsigned short f2b(float f) {
    union { float f; unsigned int u; } v; v.f = f;
    unsigned int u = v.u;
    unsigned int r = (u + 0x7fffu + ((u >> 16) & 1u)) >> 16;
    return (unsigned short)r;
}
__device__ __forceinline__ float b2f(unsigned short h) {
    union { unsigned int u; float f; } v; v.u = ((unsigned int)h) << 16;
    return v.f;
}

// ---------------- zero statb + cursor ----------------

__global__ __launch_bounds__(256) void zero_kernel(int* __restrict__ base) {
    int i = blockIdx.x * 256 + threadIdx.x;
    if (i < ZERO_N) base[i] = 0;
}

// ---------------- setup: pool/cvt of x + ELL fill + prep_weights + gptr ----------------

__global__ __launch_bounds__(256) void setup_kernel(const int* __restrict__ src,
                                                    const int* __restrict__ dst,
                                                    int* __restrict__ cursor,
                                                    int* __restrict__ ell,
                                                    const float* __restrict__ Wc1,
                                                    const float* __restrict__ Wc2,
                                                    unsigned short* __restrict__ WTb,
                                                    const int* __restrict__ batch,
                                                    int* __restrict__ gptr,
                                                    const float* __restrict__ x,
                                                    unsigned short* __restrict__ xb,
                                                    float* __restrict__ pooled0) {
    int b = blockIdx.x;
    if (b < GG) {
        // one block per graph: bf16-convert rows + pool raw x (launched first: streams HBM
        // while the edge-fill blocks wait on atomics)
        __shared__ float2 red[4][64];
        const int g = b;
        int lo = 0, hi = NN;
        while (lo < hi) { int mid = (lo + hi) >> 1; if (batch[mid] < g) lo = mid + 1; else hi = mid; }
        int beg = lo;
        hi = NN;
        while (lo < hi) { int mid = (lo + hi) >> 1; if (batch[mid] < g + 1) lo = mid + 1; else hi = mid; }
        int end = lo;
        int wave = threadIdx.x >> 6, lane = threadIdx.x & 63;
        float ax = 0.f, ay = 0.f;
        for (int r = beg + wave; r < end; r += 4) {
            float2 v = ((const float2*)(x + (size_t)r * DD))[lane];
            ax += v.x; ay += v.y;
            ((unsigned int*)(xb + (size_t)r * DD))[lane] =
                (unsigned int)f2b(v.x) | ((unsigned int)f2b(v.y) << 16);
        }
        red[wave][lane] = make_float2(ax, ay);
        __syncthreads();
        if (threadIdx.x < 64) {
            float2 a = red[0][lane], bb = red[1][lane], c = red[2][lane], d = red[3][lane];
            ((float2*)pooled0)[(size_t)g * 64 + lane] =
                make_float2(a.x + bb.x + c.x + d.x, a.y + bb.y + c.y + d.y);
        }
    } else if (b < GG + EB_BLOCKS) {
        int e = (b - GG) * 256 + threadIdx.x;
        if (e < EE) {
            int d = dst[e];
            int slot = atomicAdd(&cursor[d], 1);
            if (slot < ELLW) ell[(size_t)d * ELLW + slot] = src[e];
        }
    } else if (b < GG + EB_BLOCKS + PW_BLOCKS) {
        int idx = (b - GG - EB_BLOCKS) * 256 + threadIdx.x;   // 131072 total
        int mat = idx >> 14;
        int n = (idx >> 7) & 127;
        int k = idx & 127;
        const float* srcp = (mat < 4) ? (Wc1 + (size_t)mat * DD * DD)
                                      : (Wc2 + (size_t)(mat - 4) * DD * DD);
        WTb[idx] = f2b(srcp[k * DD + n]);
    } else {
        int g = (b - GG - EB_BLOCKS - PW_BLOCKS) * 256 + threadIdx.x;
        if (g > GG) return;
        int lo = 0, hi = NN;
        while (lo < hi) {
            int mid = (lo + hi) >> 1;
            if (batch[mid] < g) lo = mid + 1; else hi = mid;
        }
        gptr[g] = lo;
    }
}

// ---------------- aggregation: 2 nodes per wave, predicated gathers ----------------
// out[n] = t(h[n]) + sum_{src} t(h[src]),  t = BN-affine+ReLU if BN else identity.
// Wave layout: slot = lane>>4 (edge slot), seg = lane&15 (16B column segment).
// nA is even; the wave handles nodes nA and nA+1.

template <bool BN>
__device__ __forceinline__ void agg_pair(int nA, const unsigned short* __restrict__ hb,
                                         const int* __restrict__ ell,
                                         const int* __restrict__ degA,
                                         const float* __restrict__ stats,
                                         const float* __restrict__ gamma,
                                         const float* __restrict__ beta,
                                         unsigned short* __restrict__ outb) {
    const int lane = threadIdx.x & 63;
    const int seg = lane & 15;
    const int slot = lane >> 4;

    float A[8], B[8];
    if (BN) {
#pragma unroll
        for (int j = 0; j < 8; ++j) {
            int c = seg * 8 + j;
            float mu = stats[c] * (1.0f / NN);
            float var = stats[DD + c] * (1.0f / NN) - mu * mu;
            A[j] = gamma[c] * rsqrtf(var + BN_EPS);
            B[j] = beta[c] - mu * A[j];
        }
    }

    const uint4* hb4 = (const uint4*)hb;            // row stride = 16 uint4
    uint4 self = hb4[(size_t)(nA + (slot == 1 ? 1 : 0)) * 16 + seg];

    float accA[8], accB[8];
#pragma unroll
    for (int j = 0; j < 8; ++j) { accA[j] = 0.f; accB[j] = 0.f; }

    const int* rowA = ell + (size_t)nA * ELLW;
    const int* rowB = rowA + ELLW;
    const int dgA = min(degA[nA], ELLW);
    const int dgB = min(degA[nA + 1], ELLW);
    const int dgM = max(dgA, dgB);

    for (int e = 0; e < dgM; e += 16) {
        bool vA[4], vB[4];
        int iA[4], iB[4];
#pragma unroll
        for (int i = 0; i < 4; ++i) {
            int t = e + i * 4 + slot;
            vA[i] = (t < dgA);
            vB[i] = (t < dgB);
            iA[i] = rowA[t];   // in-bounds (<= ELLW-1); value unused when !vA
            iB[i] = rowB[t];
        }
        uint4 a[4], b[4];
#pragma unroll
        for (int i = 0; i < 4; ++i) {
            if (vA[i]) a[i] = hb4[(size_t)iA[i] * 16 + seg];
        }
#pragma unroll
        for (int i = 0; i < 4; ++i) {
            if (vB[i]) b[i] = hb4[(size_t)iB[i] * 16 + seg];
        }
#pragma unroll
        for (int i = 0; i < 4; ++i) {
            if (vA[i]) {
#pragma unroll
                for (int j = 0; j < 4; ++j) {
                    unsigned int u = ((unsigned int*)&a[i])[j];
                    float x = b2f((unsigned short)(u & 0xffff));
                    float y = b2f((unsigned short)(u >> 16));
                    if (BN) {
                        x = fmaxf(0.f, fmaf(x, A[2 * j], B[2 * j]));
                        y = fmaxf(0.f, fmaf(y, A[2 * j + 1], B[2 * j + 1]));
                    }
                    accA[2 * j] += x;
                    accA[2 * j + 1] += y;
                }
            }
            if (vB[i]) {
#pragma unroll
                for (int j = 0; j < 4; ++j) {
                    unsigned int u = ((unsigned int*)&b[i])[j];
                    float x = b2f((unsigned short)(u & 0xffff));
                    float y = b2f((unsigned short)(u >> 16));
                    if (BN) {
                        x = fmaxf(0.f, fmaf(x, A[2 * j], B[2 * j]));
                        y = fmaxf(0.f, fmaf(y, A[2 * j + 1], B[2 * j + 1]));
                    }
                    accB[2 * j] += x;
                    accB[2 * j + 1] += y;
                }
            }
        }
    }

#pragma unroll
    for (int j = 0; j < 8; ++j) {
        accA[j] += __shfl_xor(accA[j], 16);
        accA[j] += __shfl_xor(accA[j], 32);
        accB[j] += __shfl_xor(accB[j], 16);
        accB[j] += __shfl_xor(accB[j], 32);
    }

    if (slot < 2) {
        uint4 o;
#pragma unroll
        for (int j = 0; j < 4; ++j) {
            unsigned int u = ((unsigned int*)&self)[j];
            float x = b2f((unsigned short)(u & 0xffff));
            float y = b2f((unsigned short)(u >> 16));
            if (BN) {
                x = fmaxf(0.f, fmaf(x, A[2 * j], B[2 * j]));
                y = fmaxf(0.f, fmaf(y, A[2 * j + 1], B[2 * j + 1]));
            }
            float sx = (slot == 0) ? accA[2 * j] : accB[2 * j];
            float sy = (slot == 0) ? accA[2 * j + 1] : accB[2 * j + 1];
            ((unsigned int*)&o)[j] =
                (unsigned int)f2b(sx + x) | ((unsigned int)f2b(sy + y) << 16);
        }
        ((uint4*)outb)[(size_t)(nA + slot) * 16 + seg] = o;
    }
}

__global__ __launch_bounds__(256) void aggregate_x(const unsigned short* __restrict__ hb,
                                                   const int* __restrict__ ell,
                                                   const int* __restrict__ degA,
                                                   unsigned short* __restrict__ outb) {
    int nA = blockIdx.x * 8 + (threadIdx.x >> 6) * 2;   // NN % 8 == 0: no bounds check
    agg_pair<false>(nA, hb, ell, degA, nullptr, nullptr, nullptr, outb);
}

// ---------------- MFMA GEMM, W in registers: Out = (bn?)(Z) @ W + bias, + stats ----------------

__global__ __launch_bounds__(256, 2) void gemm_mfma(
    const unsigned short* __restrict__ Ab,   // [NN][128] bf16
    const unsigned short* __restrict__ WTb,  // [128][128] bf16 (WT[n][k])
    const float* __restrict__ bias,
    const float* __restrict__ bnStatsIn,     // null => raw input
    const float* __restrict__ gamma, const float* __restrict__ beta,
    unsigned short* __restrict__ Outb,       // [NN][128] bf16
    float* __restrict__ statsOut)            // [0..127]=colsum, [128..255]=colsumsq
{
    __shared__ unsigned short As[128 * 128];  // 32 KB, XOR-swizzled rows
    __shared__ float AbnS[DD], BbnS[DD];
    __shared__ float colred[2][DD];

    const int tid = threadIdx.x;
    const int row0 = blockIdx.x * 128;
    const bool doBn = (bnStatsIn != nullptr);
    const int lane = tid & 63;
    const int fr = lane & 15, fq = lane >> 4;

    // B fragments: all of W in registers (32 KB total, L2-hot). 8n x 4kk x 16B/lane.
    short8 bfrag[8][4];
#pragma unroll
    for (int n = 0; n < 8; ++n)
#pragma unroll
        for (int kk = 0; kk < 4; ++kk)
            bfrag[n][kk] = *(const short8*)((const char*)WTb + (n * 16 + fr) * 256 + kk * 64 + fq * 16);

    if (tid < DD) {
        colred[0][tid] = 0.f;
        colred[1][tid] = 0.f;
        if (doBn) {
            float mu = bnStatsIn[tid] * (1.0f / NN);
            float var = bnStatsIn[DD + tid] * (1.0f / NN) - mu * mu;
            float A = gamma[tid] * rsqrtf(var + BN_EPS);
            AbnS[tid] = A;
            BbnS[tid] = beta[tid] - mu * A;
        }
    }
    if (doBn) __syncthreads();

    // stage A tile (optional BN+ReLU on load)
#pragma unroll
    for (int i = 0; i < 8; ++i) {
        int c = tid + i * 256;
        int row = c >> 4, seg = c & 15;
        int gr = row0 + row;
        uint4 v = make_uint4(0u, 0u, 0u, 0u);
        if (gr < NN) v = ((const uint4*)(Ab + (size_t)gr * DD))[seg];
        if (doBn) {
            int k0 = seg * 8;
#pragma unroll
            for (int e = 0; e < 4; ++e) {
                unsigned int u = ((unsigned int*)&v)[e];
                int cidx = k0 + 2 * e;
                float lo = fmaxf(0.f, fmaf(b2f((unsigned short)(u & 0xffff)), AbnS[cidx], BbnS[cidx]));
                float hi = fmaxf(0.f, fmaf(b2f((unsigned short)(u >> 16)), AbnS[cidx + 1], BbnS[cidx + 1]));
                ((unsigned int*)&v)[e] = (unsigned int)f2b(lo) | ((unsigned int)f2b(hi) << 16);
            }
        }
        int byte = (row * 256 + seg * 16) ^ ((row & 7) << 4);
        *(uint4*)((char*)As + byte) = v;
    }
    __syncthreads();

    const int wave = tid >> 6;
    const int wr0 = wave * 32;

    f32x4 acc[2][8];
#pragma unroll
    for (int m = 0; m < 2; ++m)
#pragma unroll
        for (int n = 0; n < 8; ++n) acc[m][n] = (f32x4)0.f;

#pragma unroll
    for (int kk = 0; kk < 4; ++kk) {
        int kbyte = kk * 64 + fq * 16;
        short8 a[2];
#pragma unroll
        for (int m = 0; m < 2; ++m) {
            int row = wr0 + m * 16 + fr;
            a[m] = *(const short8*)((const char*)As + ((row * 256 + kbyte) ^ ((row & 7) << 4)));
        }
#pragma unroll
        for (int m = 0; m < 2; ++m)
#pragma unroll
            for (int n = 0; n < 8; ++n)
                acc[m][n] = __builtin_amdgcn_mfma_f32_16x16x32_bf16(a[m], bfrag[n][kk], acc[m][n], 0, 0, 0);
    }

    float bias_n[8], s[8], q[8];
#pragma unroll
    for (int n = 0; n < 8; ++n) {
        bias_n[n] = bias[n * 16 + fr];
        s[n] = 0.f;
        q[n] = 0.f;
    }
#pragma unroll
    for (int m = 0; m < 2; ++m) {
        int rbase = row0 + wr0 + m * 16 + fq * 4;
#pragma unroll
        for (int j = 0; j < 4; ++j) {
            int gr = rbase + j;
            if (gr < NN) {
#pragma unroll
                for (int n = 0; n < 8; ++n) {
                    float o = acc[m][n][j] + bias_n[n];
                    Outb[(size_t)gr * DD + n * 16 + fr] = f2b(o);
                    s[n] += o;
                    q[n] += o * o;
                }
            }
        }
    }
#pragma unroll
    for (int n = 0; n < 8; ++n) {
        s[n] += __shfl_xor(s[n], 16);
        s[n] += __shfl_xor(s[n], 32);
        q[n] += __shfl_xor(q[n], 16);
        q[n] += __shfl_xor(q[n], 32);
    }
    if (fq == 0) {
#pragma unroll
        for (int n = 0; n < 8; ++n) {
            atomicAdd(&colred[0][n * 16 + fr], s[n]);
            atomicAdd(&colred[1][n * 16 + fr], q[n]);
        }
    }
    __syncthreads();
    if (tid < DD) {
        atomicAdd(&statsOut[tid], colred[0][tid]);
        atomicAdd(&statsOut[DD + tid], colred[1][tid]);
    }
}

// ---------------- post_layer: bn_pool (blocks < GG) + next-layer aggregate (rest) ----------------

template <bool LAST>
__global__ __launch_bounds__(256) void post_layer(
    const unsigned short* __restrict__ Z,      // z2b of this layer
    const float* __restrict__ stats,           // statb (2l+1)
    const float* __restrict__ gamma,           // g_out[l]
    const float* __restrict__ beta,            // b_out[l]
    const int* __restrict__ gptr,
    const int* __restrict__ ell,
    const int* __restrict__ degA,
    float* __restrict__ pooledDst,             // pooled + (l+1)*GG*DD
    unsigned short* __restrict__ aggOut,       // aggb for next layer (unused if LAST)
    const float* __restrict__ pooledAll,       // pooled base (LAST only)
    const float* __restrict__ fcW,
    const float* __restrict__ fcb,
    float* __restrict__ out)
{
    const int bid = blockIdx.x;
    if (bid < GG) {
        __shared__ float2 red[4][64];
        __shared__ float p4[DD];
        const int g = bid;
        const int wave = threadIdx.x >> 6, lane = threadIdx.x & 63;
        const int c0 = lane * 2, c1 = c0 + 1;
        float mu0 = stats[c0] * (1.0f / NN);
        float var0 = stats[DD + c0] * (1.0f / NN) - mu0 * mu0;
        float A0 = gamma[c0] * rsqrtf(var0 + BN_EPS);
        float B0 = beta[c0] - mu0 * A0;
        float mu1 = stats[c1] * (1.0f / NN);
        float var1 = stats[DD + c1] * (1.0f / NN) - mu1 * mu1;
        float A1 = gamma[c1] * rsqrtf(var1 + BN_EPS);
        float B1 = beta[c1] - mu1 * A1;

        float ax = 0.f, ay = 0.f;
        int beg = gptr[g], end = gptr[g + 1];
        for (int r = beg + wave; r < end; r += 4) {
            unsigned int u = ((const unsigned int*)(Z + (size_t)r * DD))[lane];
            ax += fmaxf(0.f, fmaf(b2f((unsigned short)(u & 0xffff)), A0, B0));
            ay += fmaxf(0.f, fmaf(b2f((unsigned short)(u >> 16)), A1, B1));
        }
        red[wave][lane] = make_float2(ax, ay);
        __syncthreads();
        if (threadIdx.x < 64) {
            float2 a = red[0][lane], b = red[1][lane], c = red[2][lane], d = red[3][lane];
            float2 r2 = make_float2(a.x + b.x + c.x + d.x, a.y + b.y + c.y + d.y);
            ((float2*)pooledDst)[(size_t)g * 64 + lane] = r2;
            if (LAST) {
                p4[c0] = r2.x;
                p4[c1] = r2.y;
            }
        }
        if (LAST) {
            __syncthreads();
            if (threadIdx.x < 64) {
                float acc[CC];
#pragma unroll
                for (int c = 0; c < CC; ++c) acc[c] = 0.f;
                for (int i = 0; i < LL + 1; ++i) {
                    const float* Wf = fcW + (size_t)i * DD * CC;
                    for (int k = lane; k < DD; k += 64) {
                        float pv = (i == LL) ? p4[k] : pooledAll[((size_t)i * GG + g) * DD + k];
                        const float* wr = Wf + k * CC;
#pragma unroll
                        for (int c = 0; c < CC; ++c) acc[c] = fmaf(pv, wr[c], acc[c]);
                    }
                }
#pragma unroll
                for (int c = 0; c < CC; ++c)
                    for (int off = 32; off > 0; off >>= 1) acc[c] += __shfl_down(acc[c], off);
                if (lane == 0) {
#pragma unroll
                    for (int c = 0; c < CC; ++c) {
                        float b = 0.f;
                        for (int i = 0; i < LL + 1; ++i) b += fcb[i * CC + c];
                        acc[c] += b;
                    }
                    float m = acc[0];
#pragma unroll
                    for (int c = 1; c < CC; ++c) m = fmaxf(m, acc[c]);
                    float se = 0.f;
#pragma unroll
                    for (int c = 0; c < CC; ++c) se += expf(acc[c] - m);
                    float lse = m + logf(se);
#pragma unroll
                    for (int c = 0; c < CC; ++c) out[(size_t)g * CC + c] = acc[c] - lse;
                }
            }
        }
    } else {
        int nA = (bid - GG) * 8 + (threadIdx.x >> 6) * 2;
        agg_pair<true>(nA, Z, ell, degA, stats, gamma, beta, aggOut);
    }
}

// ---------------- launch ----------------

extern "C" void kernel_launch(void* const* d_in, const int* in_sizes, int n_in,
                              void* d_out, int out_size, void* d_ws, size_t ws_size,
                              hipStream_t stream) {
    const float* x     = (const float*)d_in[0];
    const int*   ei    = (const int*)d_in[1];
    const int*   batch = (const int*)d_in[2];
    const float* Wc1   = (const float*)d_in[3];
    const float* bc1   = (const float*)d_in[4];
    const float* Wc2   = (const float*)d_in[5];
    const float* bc2   = (const float*)d_in[6];
    const float* g_mid = (const float*)d_in[7];
    const float* b_mid = (const float*)d_in[8];
    const float* g_out = (const float*)d_in[9];
    const float* b_out = (const float*)d_in[10];
    const float* fcW   = (const float*)d_in[11];
    const float* fcb   = (const float*)d_in[12];
    float* out = (float*)d_out;

    char* p = (char*)d_ws;
    unsigned short* xb   = (unsigned short*)p; p += (size_t)NN * DD * 2;
    unsigned short* aggb = (unsigned short*)p; p += (size_t)NN * DD * 2;
    unsigned short* z1b  = (unsigned short*)p; p += (size_t)NN * DD * 2;
    unsigned short* z2b  = (unsigned short*)p; p += (size_t)NN * DD * 2;
    unsigned short* WTb  = (unsigned short*)p; p += (size_t)8 * DD * DD * 2;
    float* pooled = (float*)p; p += (size_t)(LL + 1) * GG * DD * 4;
    float* statb  = (float*)p; p += 8 * 256 * 4;   // contiguous with cursor: joint zero
    int* cursor = (int*)p; p += (size_t)NN * 4;    // doubles as degree array
    int* ell    = (int*)p; p += (size_t)NN * ELLW * 4;
    int* gptr   = (int*)p; p += (size_t)(GG + 16) * 4;

    const int* src = ei;
    const int* dst = ei + EE;

    zero_kernel<<<ZERO_BLOCKS, 256, 0, stream>>>((int*)statb);
    setup_kernel<<<GG + EB_BLOCKS + PW_BLOCKS + GP_BLOCKS, 256, 0, stream>>>(
        src, dst, cursor, ell, Wc1, Wc2, WTb, batch, gptr, x, xb, pooled);

    aggregate_x<<<AGG_BLOCKS, 256, 0, stream>>>(xb, ell, cursor, aggb);
    for (int l = 0; l < LL; ++l) {
        gemm_mfma<<<(NN + 127) / 128, 256, 0, stream>>>(
            aggb, WTb + (size_t)l * DD * DD, bc1 + (size_t)l * DD,
            nullptr, nullptr, nullptr,
            z1b, statb + (size_t)(2 * l) * 256);
        gemm_mfma<<<(NN + 127) / 128, 256, 0, stream>>>(
            z1b, WTb + (size_t)(4 + l) * DD * DD, bc2 + (size_t)l * DD,
            statb + (size_t)(2 * l) * 256, g_mid + (size_t)l * DD, b_mid + (size_t)l * DD,
            z2b, statb + (size_t)(2 * l + 1) * 256);
        if (l < LL - 1) {
            post_layer<false><<<GG + AGG_BLOCKS, 256, 0, stream>>>(
                z2b, statb + (size_t)(2 * l + 1) * 256,
                g_out + (size_t)l * DD, b_out + (size_t)l * DD,
                gptr, ell, cursor,
                pooled + (size_t)(l + 1) * GG * DD, aggb,
                nullptr, nullptr, nullptr, nullptr);
        } else {
            post_layer<true><<<GG, 256, 0, stream>>>(
                z2b, statb + (size_t)(2 * l + 1) * 256,
                g_out + (size_t)l * DD, b_out + (size_t)l * DD,
                gptr, ell, cursor,
                pooled + (size_t)(l + 1) * GG * DD, nullptr,
                pooled, fcW, fcb, out);
        }
    }
}